// Round 1
// baseline (437.040 us; speedup 1.0000x reference)
//
#include <hip/hip_runtime.h>
#include <hip/hip_bf16.h>

// Problem constants (match reference setup_inputs)
#define BATCH 8192
#define HID   512
#define DEPTH 16

// One block per sample. 256 threads = 4 waves. Each wave computes 4 of the 16
// path-node logits (length-512 dot products), then thread 0 does the BCE +
// mask + per-word mean and writes per_word/B to the partial buffer (or
// atomically accumulates into out if no workspace).
__global__ __launch_bounds__(256) void hsm_main_kernel(
    const float* __restrict__ hidden,       // [B, H]
    const int*   __restrict__ target,       // [B]
    const float* __restrict__ weights,      // [V, D, H]
    const float* __restrict__ codes,        // [V, D]
    const int*   __restrict__ lengths,      // [V]
    float*       __restrict__ partial,      // [B] or nullptr
    float*       __restrict__ out_atomic)   // scalar or nullptr
{
    __shared__ float sh[HID];
    __shared__ float slog[DEPTH];

    const int b   = blockIdx.x;
    const int tid = threadIdx.x;
    const int w   = target[b];

    // Stage hidden row into LDS: 512 floats / 256 threads = 1 float2 each.
    const float2* hrow = (const float2*)(hidden + (size_t)b * HID);
    ((float2*)sh)[tid] = hrow[tid];
    __syncthreads();

    const int wave = tid >> 6;
    const int lane = tid & 63;
    const float4* shv = (const float4*)sh;

#pragma unroll
    for (int di = 0; di < 4; ++di) {
        const int d = wave * 4 + di;
        const float4* wrow =
            (const float4*)(weights + ((size_t)w * DEPTH + d) * HID);
        float acc = 0.0f;
#pragma unroll
        for (int p = 0; p < 2; ++p) {
            const int idx = p * 64 + lane;     // 128 float4s per row
            float4 wv = wrow[idx];
            float4 hv = shv[idx];
            acc = fmaf(wv.x, hv.x, acc);
            acc = fmaf(wv.y, hv.y, acc);
            acc = fmaf(wv.z, hv.z, acc);
            acc = fmaf(wv.w, hv.w, acc);
        }
        // Wave-64 shuffle reduction.
#pragma unroll
        for (int off = 32; off > 0; off >>= 1)
            acc += __shfl_down(acc, off, 64);
        if (lane == 0) slog[d] = acc;
    }
    __syncthreads();

    if (tid == 0) {
        const int L = lengths[w];
        const float* crow = codes + (size_t)w * DEPTH;
        float s = 0.0f;
#pragma unroll
        for (int d = 0; d < DEPTH; ++d) {
            if (d < L) {
                const float x = slog[d];
                const float t = crow[d];
                // stable BCE-with-logits: max(x,0) - x*t + log1p(exp(-|x|))
                s += fmaxf(x, 0.0f) - x * t + log1pf(expf(-fabsf(x)));
            }
        }
        const float v = (s / (float)L) * (1.0f / (float)BATCH);
        if (partial) partial[b] = v;
        else         atomicAdd(out_atomic, v);
    }
}

// Deterministic final reduction of the 8192 per-sample partials.
__global__ __launch_bounds__(256) void hsm_reduce_kernel(
    const float* __restrict__ partial, float* __restrict__ out)
{
    __shared__ float sdata[256];
    float s = 0.0f;
    for (int i = threadIdx.x; i < BATCH; i += 256) s += partial[i];
    sdata[threadIdx.x] = s;
    __syncthreads();
#pragma unroll
    for (int stride = 128; stride > 0; stride >>= 1) {
        if (threadIdx.x < stride)
            sdata[threadIdx.x] += sdata[threadIdx.x + stride];
        __syncthreads();
    }
    if (threadIdx.x == 0) out[0] = sdata[0];
}

__global__ void hsm_zero_kernel(float* out) { out[0] = 0.0f; }

extern "C" void kernel_launch(void* const* d_in, const int* in_sizes, int n_in,
                              void* d_out, int out_size, void* d_ws, size_t ws_size,
                              hipStream_t stream)
{
    const float* hidden  = (const float*)d_in[0];
    const int*   target  = (const int*)  d_in[1];
    const float* weights = (const float*)d_in[2];
    const float* codes   = (const float*)d_in[3];
    const int*   lengths = (const int*)  d_in[4];
    float* out = (float*)d_out;

    if (ws_size >= BATCH * sizeof(float)) {
        float* partial = (float*)d_ws;
        hsm_main_kernel<<<BATCH, 256, 0, stream>>>(
            hidden, target, weights, codes, lengths, partial, nullptr);
        hsm_reduce_kernel<<<1, 256, 0, stream>>>(partial, out);
    } else {
        hsm_zero_kernel<<<1, 1, 0, stream>>>(out);
        hsm_main_kernel<<<BATCH, 256, 0, stream>>>(
            hidden, target, weights, codes, lengths, nullptr, out);
    }
}

// Round 2
// 425.563 us; speedup vs baseline: 1.0270x; 1.0270x over previous
//
#include <hip/hip_runtime.h>
#include <hip/hip_bf16.h>

// Problem constants (match reference setup_inputs)
#define BATCH 8192
#define HID   512
#define DEPTH 16

// One WAVE per sample: 2048 blocks x 256 threads (4 waves). No LDS, no
// barriers. Each lane holds 8 floats of the hidden row in registers
// (float4 at [lane] and [lane+64] of the 128-float4 row). For each of the
// 16 path nodes: coalesced float4 weight loads, 8 FMAs, butterfly shuffle
// reduction; the reduced logit for node d is parked on lane d. Lanes 0-15
// then evaluate the stable BCE in parallel, a 4-step shuffle reduces the
// masked sum, and lane 0 writes per_word/(L*B) to the partial buffer.
__global__ __launch_bounds__(256) void hsm_main_kernel(
    const float* __restrict__ hidden,       // [B, H]
    const int*   __restrict__ target,       // [B]
    const float* __restrict__ weights,      // [V, D, H]
    const float* __restrict__ codes,        // [V, D]
    const int*   __restrict__ lengths,      // [V]
    float*       __restrict__ partial)      // [B]
{
    const int tid  = threadIdx.x;
    const int wave = tid >> 6;
    const int lane = tid & 63;
    const int b    = blockIdx.x * 4 + wave;
    const int w    = target[b];            // broadcast load, all lanes same addr

    // Hidden row in registers: 512 floats = 128 float4; lane i holds [i], [i+64].
    const float4* hrow = (const float4*)(hidden + (size_t)b * HID);
    const float4 h0 = hrow[lane];
    const float4 h1 = hrow[lane + 64];

    const float4* wbase = (const float4*)(weights + (size_t)w * (DEPTH * HID));

    float xmine = 0.0f;                     // lane d (d<16) ends up holding logit d
#pragma unroll 4
    for (int d = 0; d < DEPTH; ++d) {
        const float4* wrow = wbase + d * (HID / 4);
        const float4 w0 = wrow[lane];
        const float4 w1 = wrow[lane + 64];
        float acc;
        acc = w0.x * h0.x;
        acc = fmaf(w0.y, h0.y, acc);
        acc = fmaf(w0.z, h0.z, acc);
        acc = fmaf(w0.w, h0.w, acc);
        acc = fmaf(w1.x, h1.x, acc);
        acc = fmaf(w1.y, h1.y, acc);
        acc = fmaf(w1.z, h1.z, acc);
        acc = fmaf(w1.w, h1.w, acc);
        // Butterfly reduction: every lane ends with the full dot product.
#pragma unroll
        for (int m = 32; m >= 1; m >>= 1)
            acc += __shfl_xor(acc, m, 64);
        xmine = (lane == d) ? acc : xmine;
    }

    const int L = lengths[w];               // broadcast load
    float v = 0.0f;
    if (lane < DEPTH && lane < L) {
        const float t = codes[(size_t)w * DEPTH + lane];
        const float x = xmine;
        // stable BCE-with-logits: max(x,0) - x*t + log1p(exp(-|x|))
        v = fmaxf(x, 0.0f) - x * t + log1pf(__expf(-fabsf(x)));
    }
    // Reduce the 16 BCE terms (lanes >=16 hold 0; xor masks <16 stay in-group).
#pragma unroll
    for (int m = 8; m >= 1; m >>= 1)
        v += __shfl_xor(v, m, 64);

    if (lane == 0)
        partial[b] = v / ((float)L * (float)BATCH);
}

// Deterministic final reduction of the 8192 per-sample partials (32 KB read).
__global__ __launch_bounds__(256) void hsm_reduce_kernel(
    const float* __restrict__ partial, float* __restrict__ out)
{
    __shared__ float sdata[256];
    float s = 0.0f;
    for (int i = threadIdx.x; i < BATCH; i += 256) s += partial[i];
    sdata[threadIdx.x] = s;
    __syncthreads();
#pragma unroll
    for (int stride = 128; stride > 0; stride >>= 1) {
        if (threadIdx.x < stride)
            sdata[threadIdx.x] += sdata[threadIdx.x + stride];
        __syncthreads();
    }
    if (threadIdx.x == 0) out[0] = sdata[0];
}

extern "C" void kernel_launch(void* const* d_in, const int* in_sizes, int n_in,
                              void* d_out, int out_size, void* d_ws, size_t ws_size,
                              hipStream_t stream)
{
    const float* hidden  = (const float*)d_in[0];
    const int*   target  = (const int*)  d_in[1];
    const float* weights = (const float*)d_in[2];
    const float* codes   = (const float*)d_in[3];
    const int*   lengths = (const int*)  d_in[4];
    float* out = (float*)d_out;
    float* partial = (float*)d_ws;          // needs BATCH*4 = 32 KB of ws

    hsm_main_kernel<<<BATCH / 4, 256, 0, stream>>>(
        hidden, target, weights, codes, lengths, partial);
    hsm_reduce_kernel<<<1, 256, 0, stream>>>(partial, out);
}

// Round 3
// 419.717 us; speedup vs baseline: 1.0413x; 1.0139x over previous
//
#include <hip/hip_runtime.h>
#include <hip/hip_bf16.h>

// Problem constants (match reference setup_inputs)
#define BATCH 8192
#define HID   512
#define DEPTH 16

// One WAVE per sample: 2048 blocks x 256 threads (4 waves). Each lane holds
// 8 floats of the hidden row in registers. Weight rows stream through a
// depth-4 rolling prefetch (8 float4 loads in flight per wave).
//
// Reduction scheme (50 shuffles/sample vs 100 for naive):
//   per node d: 2 xor steps (masks 32,16) -> lane l holds coset partial
//   S_d[l&15]; quadrant q=l>>4 captures node d=4t+q into slot y[t];
//   4 batched xor reductions (masks 1,2,4,8) then finish 4 nodes at once:
//   y[t] = logit_{4t+q} replicated across quadrant q.
// BCE computed redundantly across lanes (4 terms each), 2 xor steps combine
// quadrants, lane 0 scales by 1/(L*BATCH). Block reduces 4 waves' values in
// LDS -> one partial per block (2048 total).
__global__ __launch_bounds__(256) void hsm_main_kernel(
    const float* __restrict__ hidden,       // [B, H]
    const int*   __restrict__ target,       // [B]
    const float* __restrict__ weights,      // [V, D, H]
    const float* __restrict__ codes,        // [V, D]
    const int*   __restrict__ lengths,      // [V]
    float*       __restrict__ partial)      // [gridDim.x]
{
    __shared__ float sblk[4];

    const int tid  = threadIdx.x;
    const int wave = tid >> 6;
    const int lane = tid & 63;
    const int q    = lane >> 4;             // quadrant 0..3
    const int b    = blockIdx.x * 4 + wave;

    int w = target[b];                      // wave-uniform
    w = __builtin_amdgcn_readfirstlane(w);  // force scalar for addressing
    int L = lengths[w];
    L = __builtin_amdgcn_readfirstlane(L);

    // Hidden row in registers: 512 floats = 128 float4; lane holds [l], [l+64].
    const float4* hrow = (const float4*)(hidden + (size_t)b * HID);
    const float4 h0 = hrow[lane];
    const float4 h1 = hrow[lane + 64];

    const float4* wbase = (const float4*)(weights + (size_t)w * (DEPTH * HID));

    // Rolling prefetch, depth 4 rows (each row: 2 float4 per lane).
    float4 wa[4], wb[4];
#pragma unroll
    for (int i = 0; i < 4; ++i) {
        const float4* wr = wbase + i * (HID / 4);
        wa[i] = wr[lane];
        wb[i] = wr[lane + 64];
    }

    float y[4];
#pragma unroll
    for (int d = 0; d < DEPTH; ++d) {
        const int s = d & 3;
        const float4 w0 = wa[s];
        const float4 w1 = wb[s];
        if (d + 4 < DEPTH) {                // prefetch row d+4 into slot s
            const float4* wr = wbase + (d + 4) * (HID / 4);
            wa[s] = wr[lane];
            wb[s] = wr[lane + 64];
        }
        float acc;
        acc = w0.x * h0.x;
        acc = fmaf(w0.y, h0.y, acc);
        acc = fmaf(w0.z, h0.z, acc);
        acc = fmaf(w0.w, h0.w, acc);
        acc = fmaf(w1.x, h1.x, acc);
        acc = fmaf(w1.y, h1.y, acc);
        acc = fmaf(w1.z, h1.z, acc);
        acc = fmaf(w1.w, h1.w, acc);
        // 2-step coset reduce: lane l -> sum over {l, l^16, l^32, l^48}.
        acc += __shfl_xor(acc, 32, 64);
        acc += __shfl_xor(acc, 16, 64);
        // Quadrant d&3 captures node d into slot d>>2.
        if (q == (d & 3)) y[d >> 2] = acc;
    }

    // Batched finish: sum the 16 coset partials (over lane&15) for 4 nodes at
    // once. After this, y[t] = logit_{4t+q}, replicated within quadrant q.
#pragma unroll
    for (int t = 0; t < 4; ++t) {
        y[t] += __shfl_xor(y[t], 1, 64);
        y[t] += __shfl_xor(y[t], 2, 64);
        y[t] += __shfl_xor(y[t], 4, 64);
        y[t] += __shfl_xor(y[t], 8, 64);
    }

    // BCE terms for nodes {q, q+4, q+8, q+12}; masked by path length.
    const float* crow = codes + (size_t)w * DEPTH;
    float s = 0.0f;
#pragma unroll
    for (int t = 0; t < 4; ++t) {
        const int d = 4 * t + q;
        if (d < L) {
            const float x = y[t];
            const float tt = crow[d];
            // stable BCE-with-logits: max(x,0) - x*t + log1p(exp(-|x|))
            s += fmaxf(x, 0.0f) - x * tt + log1pf(__expf(-fabsf(x)));
        }
    }
    // Combine the 4 quadrants (each holds its own partial, replicated).
    s += __shfl_xor(s, 16, 64);
    s += __shfl_xor(s, 32, 64);

    if (lane == 0)
        sblk[wave] = s / ((float)L * (float)BATCH);
    __syncthreads();
    if (tid == 0)
        partial[blockIdx.x] = sblk[0] + sblk[1] + sblk[2] + sblk[3];
}

// Deterministic final reduction of the 2048 per-block partials (8 KB read).
__global__ __launch_bounds__(256) void hsm_reduce_kernel(
    const float* __restrict__ partial, float* __restrict__ out)
{
    __shared__ float sdata[256];
    float s = 0.0f;
    for (int i = threadIdx.x; i < BATCH / 4; i += 256) s += partial[i];
    sdata[threadIdx.x] = s;
    __syncthreads();
#pragma unroll
    for (int stride = 128; stride > 0; stride >>= 1) {
        if (threadIdx.x < stride)
            sdata[threadIdx.x] += sdata[threadIdx.x + stride];
        __syncthreads();
    }
    if (threadIdx.x == 0) out[0] = sdata[0];
}

extern "C" void kernel_launch(void* const* d_in, const int* in_sizes, int n_in,
                              void* d_out, int out_size, void* d_ws, size_t ws_size,
                              hipStream_t stream)
{
    const float* hidden  = (const float*)d_in[0];
    const int*   target  = (const int*)  d_in[1];
    const float* weights = (const float*)d_in[2];
    const float* codes   = (const float*)d_in[3];
    const int*   lengths = (const int*)  d_in[4];
    float* out = (float*)d_out;
    float* partial = (float*)d_ws;          // needs (BATCH/4)*4 = 8 KB of ws

    hsm_main_kernel<<<BATCH / 4, 256, 0, stream>>>(
        hidden, target, weights, codes, lengths, partial);
    hsm_reduce_kernel<<<1, 256, 0, stream>>>(partial, out);
}